// Round 2
// baseline (502.992 us; speedup 1.0000x reference)
//
#include <hip/hip_runtime.h>
#include <math.h>

#define BB 16
#define CC 512
#define HWN 4096
#define INNER 256
#define EPSV 1e-5f

__device__ __forceinline__ float wave_sum(float s) {
    for (int off = 32; off; off >>= 1) s += __shfl_down(s, off);
    return s;
}
__device__ __forceinline__ float block_sum(float v, volatile float* s_red) {
    for (int off = 32; off; off >>= 1) v += __shfl_down(v, off);
    __syncthreads();
    if ((threadIdx.x & 63) == 0) s_red[threadIdx.x >> 6] = v;
    __syncthreads();
    return s_red[0] + s_red[1] + s_red[2] + s_red[3];
}
__device__ __forceinline__ float block_max(float v, volatile float* s_red) {
    for (int off = 32; off; off >>= 1) v = fmaxf(v, __shfl_down(v, off));
    __syncthreads();
    if ((threadIdx.x & 63) == 0) s_red[threadIdx.x >> 6] = v;
    __syncthreads();
    return fmaxf(fmaxf(s_red[0], s_red[1]), fmaxf(s_red[2], s_red[3]));
}
__device__ __forceinline__ float fsigmoid(float v) {
    return __builtin_amdgcn_rcpf(1.f + __expf(-v));
}

// ---- kA: pass 1 over x. No atomics, no memset.
// cm_part[b][ch][hw]   = sum_{c in 256-half} x[b,c,hw] * Wcq[c]
// xsum_part[b][hwblk][c] = sum_{hw in 256-tile} x[b,c,hw]
__global__ __launch_bounds__(256) void kA(
    const float* __restrict__ x, const float* __restrict__ wcq,
    float* __restrict__ cm_part, float* __restrict__ xsum_part)
{
    const int t = threadIdx.x, lane = t & 63, w = t >> 6;
    const int hw0 = blockIdx.x * 256;
    const int ch  = blockIdx.y;
    const int c0  = ch * 256;
    const int b   = blockIdx.z;
    __shared__ float s_w[256];
    __shared__ float s_cm[4][256];
    s_w[t] = wcq[c0 + t];
    __syncthreads();
    const float* xb = x + ((size_t)b * CC + c0) * HWN + hw0 + lane * 4;
    float* xsp = xsum_part + ((size_t)b * 16 + blockIdx.x) * CC + c0;
    float4 acc = {0.f, 0.f, 0.f, 0.f};
    #pragma unroll 8
    for (int ci = 0; ci < 64; ++ci) {
        const int cl = w + ci * 4;                 // wave w owns rows w, w+4, ...
        float4 v = *(const float4*)(xb + (size_t)cl * HWN);
        const float wc = s_w[cl];
        acc.x = fmaf(v.x, wc, acc.x); acc.y = fmaf(v.y, wc, acc.y);
        acc.z = fmaf(v.z, wc, acc.z); acc.w = fmaf(v.w, wc, acc.w);
        float s = (v.x + v.y) + (v.z + v.w);
        s = wave_sum(s);
        if (lane == 0) xsp[cl] = s;                // plain store, no atomic
    }
    *(float4*)&s_cm[w][lane * 4] = acc;
    __syncthreads();
    cm_part[((size_t)b * 2 + ch) * HWN + hw0 + t] =
        (s_cm[0][t] + s_cm[1][t]) + (s_cm[2][t] + s_cm[3][t]);
}

// ---- kB: per-b fused small stage (replaces k2a + k_mv512 + k2c).
__global__ __launch_bounds__(256) void kB(
    const float* __restrict__ Wsq, const float* __restrict__ Wsv,
    const float* __restrict__ cm_part, const float* __restrict__ xsum_part,
    float* __restrict__ cmstats, float* __restrict__ wsv_eff)
{
    const int b = blockIdx.x, t = threadIdx.x, lane = t & 63, w = t >> 6;
    __shared__ float s_red[4];
    __shared__ float s_x[CC];
    __shared__ float s_avg[INNER];
    __shared__ float s_sm[INNER];
    // 1. reduce xsum partials (16 hw-blocks)
    float a0 = 0.f, a1 = 0.f;
    const float* xp = xsum_part + (size_t)b * 16 * CC;
    #pragma unroll
    for (int blk = 0; blk < 16; ++blk) {
        a0 += xp[blk * CC + t];
        a1 += xp[blk * CC + t + 256];
    }
    s_x[t] = a0; s_x[t + 256] = a1;
    // 2. cm softmax stats over HW (two halves summed on the fly)
    const float* c0p = cm_part + (size_t)b * 2 * HWN;
    const float* c1p = c0p + HWN;
    float lmax = -1e30f;
    #pragma unroll 4
    for (int i = t; i < HWN; i += 256) lmax = fmaxf(lmax, c0p[i] + c1p[i]);
    lmax = block_max(lmax, s_red);
    float lsum = 0.f;
    #pragma unroll 4
    for (int i = t; i < HWN; i += 256) lsum += __expf(c0p[i] + c1p[i] - lmax);
    lsum = block_sum(lsum, s_red);
    if (t == 0) {
        cmstats[2 * b]     = lmax;
        cmstats[2 * b + 1] = __builtin_amdgcn_rcpf(lsum);
    }
    __syncthreads();
    // 3. avg_logits[k] = Wsq[k,:] . s_x / HWN   (wave per k, 64 k each)
    float4 x0 = *(const float4*)&s_x[lane * 4];
    float4 x1 = *(const float4*)&s_x[256 + lane * 4];
    for (int i = 0; i < 64; ++i) {
        const int k = w * 64 + i;
        const float* row = Wsq + (size_t)k * CC + lane * 4;
        float4 q0 = *(const float4*)(row);
        float4 q1 = *(const float4*)(row + 256);
        float s = fmaf(q0.x,x0.x, fmaf(q0.y,x0.y, fmaf(q0.z,x0.z, q0.w*x0.w)))
                + fmaf(q1.x,x1.x, fmaf(q1.y,x1.y, fmaf(q1.z,x1.z, q1.w*x1.w)));
        s = wave_sum(s);
        if (lane == 0) s_avg[k] = s * (1.0f / HWN);
    }
    __syncthreads();
    // 4. softmax over 256 inner channels
    float a = s_avg[t];
    float m = block_max(a, s_red);
    float e = __expf(a - m);
    float ssum = block_sum(e, s_red);
    s_sm[t] = e * __builtin_amdgcn_rcpf(ssum);
    __syncthreads();
    // 5. wsv_eff[b,c] = sum_k s_sm[k] * Wsv[k,c]
    float acc0 = 0.f, acc1 = 0.f;
    #pragma unroll 8
    for (int k = 0; k < INNER; ++k) {
        const float sk = s_sm[k];
        acc0 = fmaf(sk, Wsv[(size_t)k * CC + t],       acc0);
        acc1 = fmaf(sk, Wsv[(size_t)k * CC + t + 256], acc1);
    }
    wsv_eff[b * CC + t]       = acc0;
    wsv_eff[b * CC + t + 256] = acc1;
}

// ---- kC: pass 2 over x. Same structure as kA.
// ctx_part[b][ch][hw] = sum_{c half} x * wsv_eff[c]
// xw_part[b][hwblk][c] = sum_{hw tile} x * softmax(cm)[hw]
__global__ __launch_bounds__(256) void kC(
    const float* __restrict__ x, const float* __restrict__ wsv_eff,
    const float* __restrict__ cm_part, const float* __restrict__ cmstats,
    float* __restrict__ ctx_part, float* __restrict__ xw_part)
{
    const int t = threadIdx.x, lane = t & 63, w = t >> 6;
    const int hw0 = blockIdx.x * 256;
    const int ch  = blockIdx.y;
    const int c0  = ch * 256;
    const int b   = blockIdx.z;
    __shared__ float s_w[256];
    __shared__ float s_m[256];
    __shared__ float s_cm[4][256];
    s_w[t] = wsv_eff[b * CC + c0 + t];
    const float cmax = cmstats[2 * b], crinv = cmstats[2 * b + 1];
    const float cmv = cm_part[(size_t)b * 2 * HWN + hw0 + t]
                    + cm_part[((size_t)b * 2 + 1) * HWN + hw0 + t];
    s_m[t] = __expf(cmv - cmax) * crinv;
    __syncthreads();
    float4 mreg = *(const float4*)&s_m[lane * 4];
    const float* xb = x + ((size_t)b * CC + c0) * HWN + hw0 + lane * 4;
    float* xwp = xw_part + ((size_t)b * 16 + blockIdx.x) * CC + c0;
    float4 acc = {0.f, 0.f, 0.f, 0.f};
    #pragma unroll 8
    for (int ci = 0; ci < 64; ++ci) {
        const int cl = w + ci * 4;
        float4 v = *(const float4*)(xb + (size_t)cl * HWN);
        const float wc = s_w[cl];
        acc.x = fmaf(v.x, wc, acc.x); acc.y = fmaf(v.y, wc, acc.y);
        acc.z = fmaf(v.z, wc, acc.z); acc.w = fmaf(v.w, wc, acc.w);
        float s = fmaf(v.x,mreg.x, fmaf(v.y,mreg.y, fmaf(v.z,mreg.z, v.w*mreg.w)));
        s = wave_sum(s);
        if (lane == 0) xwp[cl] = s;
    }
    *(float4*)&s_cm[w][lane * 4] = acc;
    __syncthreads();
    ctx_part[((size_t)b * 2 + ch) * HWN + hw0 + t] =
        (s_cm[0][t] + s_cm[1][t]) + (s_cm[2][t] + s_cm[3][t]);
}

// ---- kD: per-b fused (replaces k_mv512 + k4b_z + LN part of k4c).
__global__ __launch_bounds__(256) void kD(
    const float* __restrict__ Wcv, const float* __restrict__ Wcz,
    const float* __restrict__ gamma, const float* __restrict__ beta,
    const float* __restrict__ xw_part, float* __restrict__ maskbuf)
{
    const int b = blockIdx.x, t = threadIdx.x, lane = t & 63, w = t >> 6;
    __shared__ float s_red[4];
    __shared__ float s_xw[CC];
    __shared__ float s_ctx[INNER];
    __shared__ float s_z[CC];
    // 1. reduce xw partials
    float a0 = 0.f, a1 = 0.f;
    const float* xp = xw_part + (size_t)b * 16 * CC;
    #pragma unroll
    for (int blk = 0; blk < 16; ++blk) {
        a0 += xp[blk * CC + t];
        a1 += xp[blk * CC + t + 256];
    }
    s_xw[t] = a0; s_xw[t + 256] = a1;
    __syncthreads();
    // 2. context[k] = Wcv[k,:] . xw   (wave per k)
    float4 x0 = *(const float4*)&s_xw[lane * 4];
    float4 x1 = *(const float4*)&s_xw[256 + lane * 4];
    for (int i = 0; i < 64; ++i) {
        const int k = w * 64 + i;
        const float* row = Wcv + (size_t)k * CC + lane * 4;
        float4 q0 = *(const float4*)(row);
        float4 q1 = *(const float4*)(row + 256);
        float s = fmaf(q0.x,x0.x, fmaf(q0.y,x0.y, fmaf(q0.z,x0.z, q0.w*x0.w)))
                + fmaf(q1.x,x1.x, fmaf(q1.y,x1.y, fmaf(q1.z,x1.z, q1.w*x1.w)));
        s = wave_sum(s);
        if (lane == 0) s_ctx[k] = s;
    }
    __syncthreads();
    // 3. z[o] = Wcz[o,:256] . context   (wave per o, 128 each)
    float4 cv = *(const float4*)&s_ctx[lane * 4];
    for (int i = 0; i < 128; ++i) {
        const int o = w * 128 + i;
        float4 q = *(const float4*)(Wcz + (size_t)o * INNER + lane * 4);
        float s = fmaf(q.x,cv.x, fmaf(q.y,cv.y, fmaf(q.z,cv.z, q.w*cv.w)));
        s = wave_sum(s);
        if (lane == 0) s_z[o] = s;
    }
    __syncthreads();
    // 4. LayerNorm -> sigmoid mask
    float z0 = s_z[t], z1 = s_z[t + 256];
    float mu = block_sum(z0 + z1, s_red) * (1.f / CC);
    float d0 = z0 - mu, d1 = z1 - mu;
    float var = block_sum(d0 * d0 + d1 * d1, s_red) * (1.f / CC);
    float rstd = rsqrtf(var + EPSV);
    maskbuf[b * CC + t]       = fsigmoid(fmaf(d0 * rstd, gamma[t],       beta[t]));
    maskbuf[b * CC + t + 256] = fsigmoid(fmaf(d1 * rstd, gamma[t + 256], beta[t + 256]));
}

// ---- kE: pass 3 over x. sigmoid(ctx) computed in-register, 16 channels/block.
__global__ __launch_bounds__(256) void kE(
    const float* __restrict__ x, const float* __restrict__ ctx_part,
    const float* __restrict__ maskbuf, float* __restrict__ out)
{
    const int t  = threadIdx.x;
    const int hw = blockIdx.x * 1024 + t * 4;
    const int c0 = blockIdx.y * 16;
    const int b  = blockIdx.z;
    float4 p0 = *(const float4*)(ctx_part + ((size_t)b * 2)     * HWN + hw);
    float4 p1 = *(const float4*)(ctx_part + ((size_t)b * 2 + 1) * HWN + hw);
    float4 sg;
    sg.x = fsigmoid(p0.x + p1.x);
    sg.y = fsigmoid(p0.y + p1.y);
    sg.z = fsigmoid(p0.z + p1.z);
    sg.w = fsigmoid(p0.w + p1.w);
    const float* mb = maskbuf + b * CC + c0;
    const size_t base = ((size_t)b * CC + c0) * HWN + hw;
    #pragma unroll 4
    for (int ci = 0; ci < 16; ++ci) {
        const float m = mb[ci];
        float4 xv = *(const float4*)(x + base + (size_t)ci * HWN);
        float4 o;
        o.x = xv.x * (m + sg.x);
        o.y = xv.y * (m + sg.y);
        o.z = xv.z * (m + sg.z);
        o.w = xv.w * (m + sg.w);
        *(float4*)(out + base + (size_t)ci * HWN) = o;
    }
}

extern "C" void kernel_launch(void* const* d_in, const int* in_sizes, int n_in,
                              void* d_out, int out_size, void* d_ws, size_t ws_size,
                              hipStream_t stream) {
    const float* x     = (const float*)d_in[0];
    const float* Wsq   = (const float*)d_in[1];
    const float* Wsv   = (const float*)d_in[2];
    const float* Wcq   = (const float*)d_in[3];
    const float* Wcv   = (const float*)d_in[4];
    const float* Wcz   = (const float*)d_in[5];
    const float* gamma = (const float*)d_in[6];
    const float* beta  = (const float*)d_in[7];
    float* out = (float*)d_out;
    float* ws  = (float*)d_ws;

    float* cm_part   = ws;             // [16][2][4096]  = 131072
    float* xsum_part = ws + 131072;    // [16][16][512]  = 131072 (reused as xw_part)
    float* ctx_part  = ws + 262144;    // [16][2][4096]  = 131072
    float* cmstats   = ws + 393216;    // 32
    float* wsv_eff   = ws + 393248;    // 8192
    float* maskbuf   = ws + 401440;    // 8192
    // total 409632 floats (~1.6 MiB); no memset required — all fully written before read

    kA<<<dim3(16, 2, BB), 256, 0, stream>>>(x, Wcq, cm_part, xsum_part);
    kB<<<BB, 256, 0, stream>>>(Wsq, Wsv, cm_part, xsum_part, cmstats, wsv_eff);
    kC<<<dim3(16, 2, BB), 256, 0, stream>>>(x, wsv_eff, cm_part, cmstats, ctx_part, xsum_part);
    kD<<<BB, 256, 0, stream>>>(Wcv, Wcz, gamma, beta, xsum_part, maskbuf);
    kE<<<dim3(4, 32, BB), 256, 0, stream>>>(x, ctx_part, maskbuf, out);
}

// Round 3
// 381.357 us; speedup vs baseline: 1.3190x; 1.3190x over previous
//
#include <hip/hip_runtime.h>
#include <math.h>

#define BB 16
#define CC 512
#define HWN 4096
#define INNER 256
#define EPSV 1e-5f

__device__ __forceinline__ float wave_sum(float s) {
    for (int off = 32; off; off >>= 1) s += __shfl_down(s, off);
    return s;
}
__device__ __forceinline__ float block_sum(float v, volatile float* s_red) {
    for (int off = 32; off; off >>= 1) v += __shfl_down(v, off);
    __syncthreads();
    if ((threadIdx.x & 63) == 0) s_red[threadIdx.x >> 6] = v;
    __syncthreads();
    return s_red[0] + s_red[1] + s_red[2] + s_red[3];
}
__device__ __forceinline__ float block_max(float v, volatile float* s_red) {
    for (int off = 32; off; off >>= 1) v = fmaxf(v, __shfl_down(v, off));
    __syncthreads();
    if ((threadIdx.x & 63) == 0) s_red[threadIdx.x >> 6] = v;
    __syncthreads();
    return fmaxf(fmaxf(s_red[0], s_red[1]), fmaxf(s_red[2], s_red[3]));
}
__device__ __forceinline__ float fsigmoid(float v) {
    return __builtin_amdgcn_rcpf(1.f + __expf(-v));
}

// ---- kA: pass 1 over x. grid (16 hw-tiles, 4 c-quarters, 16 b) = 1024 blocks.
// cm_part[b][q][hw]      = sum_{c in 128-quarter} x[b,c,hw] * Wcq[c]
// xsum_part[b][hwblk][c] = sum_{hw in 256-tile} x[b,c,hw]
__global__ __launch_bounds__(256) void kA(
    const float* __restrict__ x, const float* __restrict__ wcq,
    float* __restrict__ cm_part, float* __restrict__ xsum_part)
{
    const int t = threadIdx.x, lane = t & 63, w = t >> 6;
    const int hw0 = blockIdx.x * 256;
    const int q   = blockIdx.y;
    const int c0  = q * 128;
    const int b   = blockIdx.z;
    __shared__ float s_w[128];
    __shared__ float s_cm[4][256];
    if (t < 128) s_w[t] = wcq[c0 + t];
    __syncthreads();
    const float* xb = x + ((size_t)b * CC + c0) * HWN + hw0 + lane * 4;
    float* xsp = xsum_part + ((size_t)b * 16 + blockIdx.x) * CC + c0;
    float4 acc = {0.f, 0.f, 0.f, 0.f};
    #pragma unroll 8
    for (int ci = 0; ci < 32; ++ci) {
        const int cl = w + ci * 4;                 // wave w owns rows w, w+4, ...
        float4 v = *(const float4*)(xb + (size_t)cl * HWN);
        const float wc = s_w[cl];
        acc.x = fmaf(v.x, wc, acc.x); acc.y = fmaf(v.y, wc, acc.y);
        acc.z = fmaf(v.z, wc, acc.z); acc.w = fmaf(v.w, wc, acc.w);
        float s = (v.x + v.y) + (v.z + v.w);
        s = wave_sum(s);
        if (lane == 0) xsp[cl] = s;                // plain store, no atomic
    }
    *(float4*)&s_cm[w][lane * 4] = acc;
    __syncthreads();
    cm_part[((size_t)b * 4 + q) * HWN + hw0 + t] =
        (s_cm[0][t] + s_cm[1][t]) + (s_cm[2][t] + s_cm[3][t]);
}

// ---- k2a: cm softmax stats per b (16 blocks)
__global__ __launch_bounds__(256) void k2a_cmstats(
    const float* __restrict__ cm_part, float* __restrict__ cmstats)
{
    const int b = blockIdx.x, t = threadIdx.x;
    __shared__ float s_red[4];
    const float* p0 = cm_part + (size_t)b * 4 * HWN;
    const float* p1 = p0 + HWN;
    const float* p2 = p1 + HWN;
    const float* p3 = p2 + HWN;
    float lmax = -1e30f;
    #pragma unroll 4
    for (int i = t; i < HWN; i += 256)
        lmax = fmaxf(lmax, (p0[i] + p1[i]) + (p2[i] + p3[i]));
    lmax = block_max(lmax, s_red);
    float lsum = 0.f;
    #pragma unroll 4
    for (int i = t; i < HWN; i += 256)
        lsum += __expf((p0[i] + p1[i]) + (p2[i] + p3[i]) - lmax);
    lsum = block_sum(lsum, s_red);
    if (t == 0) {
        cmstats[2 * b]     = lmax;
        cmstats[2 * b + 1] = __builtin_amdgcn_rcpf(lsum);
    }
}

// ---- k_mvp: y[b,k0+k] = scale * W[k,:512] . (reduced partials v[b])
// grid (BB, 4 k-tiles of 64). Reduces the 16 hw-block partials in-block.
__global__ __launch_bounds__(256) void k_mvp(
    const float* __restrict__ W, const float* __restrict__ vpart,
    float* __restrict__ y, float scale)
{
    const int b = blockIdx.x, t = threadIdx.x, lane = t & 63, w = t >> 6;
    const int k0 = blockIdx.y * 64;
    __shared__ float s_v[CC];
    const float* xp = vpart + (size_t)b * 16 * CC;
    float a0 = 0.f, a1 = 0.f;
    #pragma unroll
    for (int blk = 0; blk < 16; ++blk) {
        a0 += xp[blk * CC + t];
        a1 += xp[blk * CC + t + 256];
    }
    s_v[t] = a0; s_v[t + 256] = a1;
    __syncthreads();
    float4 x0 = *(const float4*)&s_v[lane * 4];
    float4 x1 = *(const float4*)&s_v[256 + lane * 4];
    #pragma unroll 8
    for (int i = 0; i < 16; ++i) {
        const int k = k0 + w * 16 + i;
        const float* row = W + (size_t)k * CC + lane * 4;
        float4 q0 = *(const float4*)(row);
        float4 q1 = *(const float4*)(row + 256);
        float s = fmaf(q0.x,x0.x, fmaf(q0.y,x0.y, fmaf(q0.z,x0.z, q0.w*x0.w)))
                + fmaf(q1.x,x1.x, fmaf(q1.y,x1.y, fmaf(q1.z,x1.z, q1.w*x1.w)));
        s = wave_sum(s);
        if (lane == 0) y[b * INNER + k] = s * scale;
    }
}

// ---- k2c: softmax(avg_logits) ; wsv_eff[b,c] = sum_k sm[k]*Wsv[k,c]
__global__ __launch_bounds__(256) void k2c_wsv(
    const float* __restrict__ Wsv, const float* __restrict__ avg_logits,
    float* __restrict__ wsv_eff)
{
    const int b = blockIdx.x, t = threadIdx.x;
    const int c = blockIdx.y * 256 + t;
    __shared__ float s_red[4];
    __shared__ float s_sm[INNER];
    float a = avg_logits[b * INNER + t];
    float m = block_max(a, s_red);
    float e = __expf(a - m);
    float s2 = block_sum(e, s_red);
    s_sm[t] = e * __builtin_amdgcn_rcpf(s2);
    __syncthreads();
    float acc = 0.f;
    #pragma unroll 8
    for (int k = 0; k < INNER; ++k)
        acc = fmaf(s_sm[k], Wsv[(size_t)k * CC + c], acc);
    wsv_eff[b * CC + c] = acc;
}

// ---- kC: pass 2 over x. grid (16, 4, 16) = 1024 blocks.
// ctx_part[b][q][hw]   = sum_{c quarter} x * wsv_eff[c]
// xw_part[b][hwblk][c] = sum_{hw tile} x * softmax(cm)[hw]
__global__ __launch_bounds__(256) void kC(
    const float* __restrict__ x, const float* __restrict__ wsv_eff,
    const float* __restrict__ cm_part, const float* __restrict__ cmstats,
    float* __restrict__ ctx_part, float* __restrict__ xw_part)
{
    const int t = threadIdx.x, lane = t & 63, w = t >> 6;
    const int hw0 = blockIdx.x * 256;
    const int q   = blockIdx.y;
    const int c0  = q * 128;
    const int b   = blockIdx.z;
    __shared__ float s_w[128];
    __shared__ float s_m[256];
    __shared__ float s_cm[4][256];
    if (t < 128) s_w[t] = wsv_eff[b * CC + c0 + t];
    const float cmax = cmstats[2 * b], crinv = cmstats[2 * b + 1];
    const size_t cb = (size_t)b * 4 * HWN + hw0 + t;
    const float cmv = (cm_part[cb] + cm_part[cb + HWN])
                    + (cm_part[cb + 2 * HWN] + cm_part[cb + 3 * HWN]);
    s_m[t] = __expf(cmv - cmax) * crinv;
    __syncthreads();
    float4 mreg = *(const float4*)&s_m[lane * 4];
    const float* xb = x + ((size_t)b * CC + c0) * HWN + hw0 + lane * 4;
    float* xwp = xw_part + ((size_t)b * 16 + blockIdx.x) * CC + c0;
    float4 acc = {0.f, 0.f, 0.f, 0.f};
    #pragma unroll 8
    for (int ci = 0; ci < 32; ++ci) {
        const int cl = w + ci * 4;
        float4 v = *(const float4*)(xb + (size_t)cl * HWN);
        const float wc = s_w[cl];
        acc.x = fmaf(v.x, wc, acc.x); acc.y = fmaf(v.y, wc, acc.y);
        acc.z = fmaf(v.z, wc, acc.z); acc.w = fmaf(v.w, wc, acc.w);
        float s = fmaf(v.x,mreg.x, fmaf(v.y,mreg.y, fmaf(v.z,mreg.z, v.w*mreg.w)));
        s = wave_sum(s);
        if (lane == 0) xwp[cl] = s;
    }
    *(float4*)&s_cm[w][lane * 4] = acc;
    __syncthreads();
    ctx_part[((size_t)b * 4 + q) * HWN + hw0 + t] =
        (s_cm[0][t] + s_cm[1][t]) + (s_cm[2][t] + s_cm[3][t]);
}

// ---- k4b: z[b,o] = Wcz[o,:256] . context[b,:]  (grid: BB x 4 o-tiles)
__global__ __launch_bounds__(256) void k4b_z(
    const float* __restrict__ Wcz, const float* __restrict__ context,
    float* __restrict__ zbuf)
{
    const int b = blockIdx.x, t = threadIdx.x, lane = t & 63, w = t >> 6;
    const int o0 = blockIdx.y * 128;
    __shared__ float s_c[INNER];
    if (t < INNER) s_c[t] = context[b * INNER + t];
    __syncthreads();
    float4 cv = *(const float4*)&s_c[lane * 4];
    #pragma unroll 8
    for (int i = 0; i < 32; ++i) {
        const int o = o0 + w * 32 + i;
        float4 qv = *(const float4*)(Wcz + (size_t)o * INNER + lane * 4);
        float s = fmaf(qv.x,cv.x, fmaf(qv.y,cv.y, fmaf(qv.z,cv.z, qv.w*cv.w)));
        s = wave_sum(s);
        if (lane == 0) zbuf[b * CC + o] = s;
    }
}

// ---- k4c: LayerNorm(z) -> sigmoid mask (16 blocks)
__global__ __launch_bounds__(256) void k4c_ln(
    const float* __restrict__ gamma, const float* __restrict__ beta,
    const float* __restrict__ zbuf, float* __restrict__ maskbuf)
{
    const int b = blockIdx.x, t = threadIdx.x;
    __shared__ float s_red[4];
    float z0 = zbuf[b * CC + t], z1 = zbuf[b * CC + t + 256];
    float mu = block_sum(z0 + z1, s_red) * (1.f / CC);
    float d0 = z0 - mu, d1 = z1 - mu;
    float var = block_sum(d0 * d0 + d1 * d1, s_red) * (1.f / CC);
    float rstd = rsqrtf(var + EPSV);
    maskbuf[b * CC + t]       = fsigmoid(fmaf(d0 * rstd, gamma[t],       beta[t]));
    maskbuf[b * CC + t + 256] = fsigmoid(fmaf(d1 * rstd, gamma[t + 256], beta[t + 256]));
}

// ---- kE: pass 3 over x. sigmoid(ctx) in-register, 16 channels per block.
__global__ __launch_bounds__(256) void kE(
    const float* __restrict__ x, const float* __restrict__ ctx_part,
    const float* __restrict__ maskbuf, float* __restrict__ out)
{
    const int t  = threadIdx.x;
    const int hw = blockIdx.x * 1024 + t * 4;
    const int c0 = blockIdx.y * 16;
    const int b  = blockIdx.z;
    const size_t pb = (size_t)b * 4 * HWN + hw;
    float4 p0 = *(const float4*)(ctx_part + pb);
    float4 p1 = *(const float4*)(ctx_part + pb + HWN);
    float4 p2 = *(const float4*)(ctx_part + pb + 2 * HWN);
    float4 p3 = *(const float4*)(ctx_part + pb + 3 * HWN);
    float4 sg;
    sg.x = fsigmoid((p0.x + p1.x) + (p2.x + p3.x));
    sg.y = fsigmoid((p0.y + p1.y) + (p2.y + p3.y));
    sg.z = fsigmoid((p0.z + p1.z) + (p2.z + p3.z));
    sg.w = fsigmoid((p0.w + p1.w) + (p2.w + p3.w));
    const float* mb = maskbuf + b * CC + c0;
    const size_t base = ((size_t)b * CC + c0) * HWN + hw;
    #pragma unroll 4
    for (int ci = 0; ci < 16; ++ci) {
        const float m = mb[ci];
        float4 xv = *(const float4*)(x + base + (size_t)ci * HWN);
        float4 o;
        o.x = xv.x * (m + sg.x);
        o.y = xv.y * (m + sg.y);
        o.z = xv.z * (m + sg.z);
        o.w = xv.w * (m + sg.w);
        *(float4*)(out + base + (size_t)ci * HWN) = o;
    }
}

extern "C" void kernel_launch(void* const* d_in, const int* in_sizes, int n_in,
                              void* d_out, int out_size, void* d_ws, size_t ws_size,
                              hipStream_t stream) {
    const float* x     = (const float*)d_in[0];
    const float* Wsq   = (const float*)d_in[1];
    const float* Wsv   = (const float*)d_in[2];
    const float* Wcq   = (const float*)d_in[3];
    const float* Wcv   = (const float*)d_in[4];
    const float* Wcz   = (const float*)d_in[5];
    const float* gamma = (const float*)d_in[6];
    const float* beta  = (const float*)d_in[7];
    float* out = (float*)d_out;
    float* ws  = (float*)d_ws;

    float* cm_part    = ws;            // [16][4][4096] = 262144
    float* xsum_part  = ws + 262144;   // [16][16][512] = 131072 (reused as xw_part)
    float* ctx_part   = ws + 393216;   // [16][4][4096] = 262144
    float* cmstats    = ws + 655360;   // 32
    float* wsv_eff    = ws + 655392;   // 8192
    float* avg_logits = ws + 663584;   // 4096
    float* context    = ws + 667680;   // 4096
    float* zbuf       = ws + 671776;   // 8192
    float* maskbuf    = ws + 679968;   // 8192
    // total ~688160 floats (~2.75 MiB); fully written before read — no memset

    kA<<<dim3(16, 4, BB), 256, 0, stream>>>(x, Wcq, cm_part, xsum_part);
    k2a_cmstats<<<BB, 256, 0, stream>>>(cm_part, cmstats);
    k_mvp<<<dim3(BB, 4), 256, 0, stream>>>(Wsq, xsum_part, avg_logits, 1.0f / HWN);
    k2c_wsv<<<dim3(BB, 2), 256, 0, stream>>>(Wsv, avg_logits, wsv_eff);
    kC<<<dim3(16, 4, BB), 256, 0, stream>>>(x, wsv_eff, cm_part, cmstats, ctx_part, xsum_part);
    k_mvp<<<dim3(BB, 4), 256, 0, stream>>>(Wcv, xsum_part, context, 1.0f);
    k4b_z<<<dim3(BB, 4), 256, 0, stream>>>(Wcz, context, zbuf);
    k4c_ln<<<BB, 256, 0, stream>>>(gamma, beta, zbuf, maskbuf);
    kE<<<dim3(4, 32, BB), 256, 0, stream>>>(x, ctx_part, maskbuf, out);
}

// Round 4
// 359.792 us; speedup vs baseline: 1.3980x; 1.0599x over previous
//
#include <hip/hip_runtime.h>
#include <math.h>

#define BB 16
#define CC 512
#define HWN 4096
#define INNER 256
#define EPSV 1e-5f

__device__ __forceinline__ float wave_sum(float s) {
    for (int off = 32; off; off >>= 1) s += __shfl_down(s, off);
    return s;
}
__device__ __forceinline__ float block_sum(float v, volatile float* s_red) {
    for (int off = 32; off; off >>= 1) v += __shfl_down(v, off);
    __syncthreads();
    if ((threadIdx.x & 63) == 0) s_red[threadIdx.x >> 6] = v;
    __syncthreads();
    return s_red[0] + s_red[1] + s_red[2] + s_red[3];
}
__device__ __forceinline__ float block_max(float v, volatile float* s_red) {
    for (int off = 32; off; off >>= 1) v = fmaxf(v, __shfl_down(v, off));
    __syncthreads();
    if ((threadIdx.x & 63) == 0) s_red[threadIdx.x >> 6] = v;
    __syncthreads();
    return fmaxf(fmaxf(s_red[0], s_red[1]), fmaxf(s_red[2], s_red[3]));
}
__device__ __forceinline__ float block_sum8(float v, volatile float* s_red) {
    for (int off = 32; off; off >>= 1) v += __shfl_down(v, off);
    __syncthreads();
    if ((threadIdx.x & 63) == 0) s_red[threadIdx.x >> 6] = v;
    __syncthreads();
    return ((s_red[0] + s_red[1]) + (s_red[2] + s_red[3]))
         + ((s_red[4] + s_red[5]) + (s_red[6] + s_red[7]));
}
__device__ __forceinline__ float fsigmoid(float v) {
    return __builtin_amdgcn_rcpf(1.f + __expf(-v));
}

// ---- kA: pass 1 over x. grid (8 hw-tiles of 512, 4 c-quarters, 16 b) = 512 blocks.
// cm_part[b][q][hw]      = sum_{c in quarter} x[b,c,hw] * Wcq[c]
// xsum_part[b][hwblk][c] = sum_{hw in 512-tile} x[b,c,hw]
// No per-iteration wave_sum: lane partials -> LDS -> one wave-local transpose reduce.
__global__ __launch_bounds__(256) void kA(
    const float* __restrict__ x, const float* __restrict__ wcq,
    float* __restrict__ cm_part, float* __restrict__ xsum_part)
{
    const int t = threadIdx.x, lane = t & 63, w = t >> 6;
    const int hw0 = blockIdx.x * 512;
    const int q   = blockIdx.y;
    const int c0  = q * 128;
    const int b   = blockIdx.z;
    __shared__ float s_w[128];
    __shared__ float s_cm[4][512];
    __shared__ float s_part[4][32][65];   // [wave][ci][lane], pitch 65: conflict-free
    if (t < 128) s_w[t] = wcq[c0 + t];
    __syncthreads();
    const float* xb = x + ((size_t)b * CC + c0) * HWN + hw0 + lane * 8;
    float4 a0 = {0,0,0,0}, a1 = a0;
    #pragma unroll 4
    for (int ci = 0; ci < 32; ++ci) {
        const int cl = w + ci * 4;
        const float* p = xb + (size_t)cl * HWN;
        float4 v0 = *(const float4*)(p);
        float4 v1 = *(const float4*)(p + 4);
        const float wc = s_w[cl];
        a0.x = fmaf(v0.x, wc, a0.x); a0.y = fmaf(v0.y, wc, a0.y);
        a0.z = fmaf(v0.z, wc, a0.z); a0.w = fmaf(v0.w, wc, a0.w);
        a1.x = fmaf(v1.x, wc, a1.x); a1.y = fmaf(v1.y, wc, a1.y);
        a1.z = fmaf(v1.z, wc, a1.z); a1.w = fmaf(v1.w, wc, a1.w);
        s_part[w][ci][lane] = ((v0.x + v0.y) + (v0.z + v0.w))
                            + ((v1.x + v1.y) + (v1.z + v1.w));
    }
    // wave-local reduce: lane l<32 + mirror lane l+32 split the 64 columns of row (l&31)
    {
        const int r = lane & 31;
        const int j0 = (lane >> 5) * 32;
        float xs = 0.f;
        #pragma unroll
        for (int j = 0; j < 32; ++j) xs += s_part[w][r][j0 + j];
        xs += __shfl_down(xs, 32);
        if (lane < 32)
            xsum_part[((size_t)b * 8 + blockIdx.x) * CC + c0 + w + r * 4] = xs;
    }
    *(float4*)&s_cm[w][lane * 8]     = a0;
    *(float4*)&s_cm[w][lane * 8 + 4] = a1;
    __syncthreads();
    float* cp = cm_part + ((size_t)b * 4 + q) * HWN + hw0;
    cp[t]       = (s_cm[0][t]       + s_cm[1][t])       + (s_cm[2][t]       + s_cm[3][t]);
    cp[t + 256] = (s_cm[0][t + 256] + s_cm[1][t + 256]) + (s_cm[2][t + 256] + s_cm[3][t + 256]);
}

// ---- kB1: grid (16, 5). y<4: avg_logits k-tile matvec; y==4: cm softmax stats.
__global__ __launch_bounds__(256) void kB1(
    const float* __restrict__ Wsq, const float* __restrict__ cm_part,
    const float* __restrict__ xsum_part,
    float* __restrict__ cmstats, float* __restrict__ avg_logits)
{
    const int b = blockIdx.x, t = threadIdx.x, lane = t & 63, w = t >> 6;
    __shared__ float s_red[4];
    __shared__ float s_v[CC];
    if (blockIdx.y == 4) {
        const float* p0 = cm_part + (size_t)b * 4 * HWN;
        const float* p1 = p0 + HWN;
        const float* p2 = p1 + HWN;
        const float* p3 = p2 + HWN;
        float lmax = -1e30f;
        #pragma unroll 4
        for (int i = t; i < HWN; i += 256)
            lmax = fmaxf(lmax, (p0[i] + p1[i]) + (p2[i] + p3[i]));
        lmax = block_max(lmax, s_red);
        float lsum = 0.f;
        #pragma unroll 4
        for (int i = t; i < HWN; i += 256)
            lsum += __expf((p0[i] + p1[i]) + (p2[i] + p3[i]) - lmax);
        lsum = block_sum(lsum, s_red);
        if (t == 0) {
            cmstats[2 * b]     = lmax;
            cmstats[2 * b + 1] = __builtin_amdgcn_rcpf(lsum);
        }
    } else {
        const int k0 = blockIdx.y * 64;
        const float* xp = xsum_part + (size_t)b * 8 * CC;
        float a0 = 0.f, a1 = 0.f;
        #pragma unroll
        for (int blk = 0; blk < 8; ++blk) {
            a0 += xp[blk * CC + t];
            a1 += xp[blk * CC + t + 256];
        }
        s_v[t] = a0; s_v[t + 256] = a1;
        __syncthreads();
        float4 x0 = *(const float4*)&s_v[lane * 4];
        float4 x1 = *(const float4*)&s_v[256 + lane * 4];
        #pragma unroll 8
        for (int i = 0; i < 16; ++i) {
            const int k = k0 + w * 16 + i;
            const float* row = Wsq + (size_t)k * CC + lane * 4;
            float4 q0 = *(const float4*)(row);
            float4 q1 = *(const float4*)(row + 256);
            float s = fmaf(q0.x,x0.x, fmaf(q0.y,x0.y, fmaf(q0.z,x0.z, q0.w*x0.w)))
                    + fmaf(q1.x,x1.x, fmaf(q1.y,x1.y, fmaf(q1.z,x1.z, q1.w*x1.w)));
            s = wave_sum(s);
            if (lane == 0) avg_logits[b * INNER + k] = s * (1.0f / HWN);
        }
    }
}

// ---- k2c: softmax(avg_logits) ; wsv_eff[b,c] = sum_k sm[k]*Wsv[k,c]
__global__ __launch_bounds__(256) void k2c_wsv(
    const float* __restrict__ Wsv, const float* __restrict__ avg_logits,
    float* __restrict__ wsv_eff)
{
    const int b = blockIdx.x, t = threadIdx.x;
    const int c = blockIdx.y * 256 + t;
    __shared__ float s_red[4];
    __shared__ float s_sm[INNER];
    float a = avg_logits[b * INNER + t];
    float m = block_max(a, s_red);
    float e = __expf(a - m);
    float s2 = block_sum(e, s_red);
    s_sm[t] = e * __builtin_amdgcn_rcpf(s2);
    __syncthreads();
    float acc = 0.f;
    #pragma unroll 8
    for (int k = 0; k < INNER; ++k)
        acc = fmaf(s_sm[k], Wsv[(size_t)k * CC + c], acc);
    wsv_eff[b * CC + c] = acc;
}

// ---- kC: pass 2 over x. grid (8, 4, 16) = 512 blocks.
// ctx_part[b][q][hw]   = sum_{c quarter} x * wsv_eff[c]
// xw_part[b][hwblk][c] = sum_{hw 512-tile} x * softmax(cm)[hw]
__global__ __launch_bounds__(256) void kC(
    const float* __restrict__ x, const float* __restrict__ wsv_eff,
    const float* __restrict__ cm_part, const float* __restrict__ cmstats,
    float* __restrict__ ctx_part, float* __restrict__ xw_part)
{
    const int t = threadIdx.x, lane = t & 63, w = t >> 6;
    const int hw0 = blockIdx.x * 512;
    const int q   = blockIdx.y;
    const int c0  = q * 128;
    const int b   = blockIdx.z;
    __shared__ float s_w[128];
    __shared__ float s_m[512];
    __shared__ float s_cm[4][512];
    __shared__ float s_part[4][32][65];
    if (t < 128) s_w[t] = wsv_eff[b * CC + c0 + t];
    const float cmax = cmstats[2 * b], crinv = cmstats[2 * b + 1];
    {
        const size_t cb = (size_t)b * 4 * HWN + hw0;
        float cmv0 = (cm_part[cb + t]           + cm_part[cb + HWN + t])
                   + (cm_part[cb + 2*HWN + t]   + cm_part[cb + 3*HWN + t]);
        float cmv1 = (cm_part[cb + t+256]         + cm_part[cb + HWN + t+256])
                   + (cm_part[cb + 2*HWN + t+256] + cm_part[cb + 3*HWN + t+256]);
        s_m[t]       = __expf(cmv0 - cmax) * crinv;
        s_m[t + 256] = __expf(cmv1 - cmax) * crinv;
    }
    __syncthreads();
    float4 m0 = *(const float4*)&s_m[lane * 8];
    float4 m1 = *(const float4*)&s_m[lane * 8 + 4];
    const float* xb = x + ((size_t)b * CC + c0) * HWN + hw0 + lane * 8;
    float4 a0 = {0,0,0,0}, a1 = a0;
    #pragma unroll 4
    for (int ci = 0; ci < 32; ++ci) {
        const int cl = w + ci * 4;
        const float* p = xb + (size_t)cl * HWN;
        float4 v0 = *(const float4*)(p);
        float4 v1 = *(const float4*)(p + 4);
        const float wc = s_w[cl];
        a0.x = fmaf(v0.x, wc, a0.x); a0.y = fmaf(v0.y, wc, a0.y);
        a0.z = fmaf(v0.z, wc, a0.z); a0.w = fmaf(v0.w, wc, a0.w);
        a1.x = fmaf(v1.x, wc, a1.x); a1.y = fmaf(v1.y, wc, a1.y);
        a1.z = fmaf(v1.z, wc, a1.z); a1.w = fmaf(v1.w, wc, a1.w);
        s_part[w][ci][lane] =
              fmaf(v0.x,m0.x, fmaf(v0.y,m0.y, fmaf(v0.z,m0.z, v0.w*m0.w)))
            + fmaf(v1.x,m1.x, fmaf(v1.y,m1.y, fmaf(v1.z,m1.z, v1.w*m1.w)));
    }
    {
        const int r = lane & 31;
        const int j0 = (lane >> 5) * 32;
        float xs = 0.f;
        #pragma unroll
        for (int j = 0; j < 32; ++j) xs += s_part[w][r][j0 + j];
        xs += __shfl_down(xs, 32);
        if (lane < 32)
            xw_part[((size_t)b * 8 + blockIdx.x) * CC + c0 + w + r * 4] = xs;
    }
    *(float4*)&s_cm[w][lane * 8]     = a0;
    *(float4*)&s_cm[w][lane * 8 + 4] = a1;
    __syncthreads();
    float* cp = ctx_part + ((size_t)b * 4 + q) * HWN + hw0;
    cp[t]       = (s_cm[0][t]       + s_cm[1][t])       + (s_cm[2][t]       + s_cm[3][t]);
    cp[t + 256] = (s_cm[0][t + 256] + s_cm[1][t + 256]) + (s_cm[2][t + 256] + s_cm[3][t + 256]);
}

// ---- kD1: context[b,k] = Wcv[k,:512] . xw  (grid: BB x 4 k-tiles)
__global__ __launch_bounds__(256) void kD1(
    const float* __restrict__ Wcv, const float* __restrict__ xw_part,
    float* __restrict__ context)
{
    const int b = blockIdx.x, t = threadIdx.x, lane = t & 63, w = t >> 6;
    const int k0 = blockIdx.y * 64;
    __shared__ float s_v[CC];
    const float* xp = xw_part + (size_t)b * 8 * CC;
    float a0 = 0.f, a1 = 0.f;
    #pragma unroll
    for (int blk = 0; blk < 8; ++blk) {
        a0 += xp[blk * CC + t];
        a1 += xp[blk * CC + t + 256];
    }
    s_v[t] = a0; s_v[t + 256] = a1;
    __syncthreads();
    float4 x0 = *(const float4*)&s_v[lane * 4];
    float4 x1 = *(const float4*)&s_v[256 + lane * 4];
    #pragma unroll 8
    for (int i = 0; i < 16; ++i) {
        const int k = k0 + w * 16 + i;
        const float* row = Wcv + (size_t)k * CC + lane * 4;
        float4 q0 = *(const float4*)(row);
        float4 q1 = *(const float4*)(row + 256);
        float s = fmaf(q0.x,x0.x, fmaf(q0.y,x0.y, fmaf(q0.z,x0.z, q0.w*x0.w)))
                + fmaf(q1.x,x1.x, fmaf(q1.y,x1.y, fmaf(q1.z,x1.z, q1.w*x1.w)));
        s = wave_sum(s);
        if (lane == 0) context[b * INNER + k] = s;
    }
}

// ---- kD2: z = Wcz.context ; LayerNorm(z) -> sigmoid mask. grid(16) x 512 thr.
__global__ __launch_bounds__(512) void kD2(
    const float* __restrict__ Wcz, const float* __restrict__ context,
    const float* __restrict__ gamma, const float* __restrict__ beta,
    float* __restrict__ maskbuf)
{
    const int b = blockIdx.x, t = threadIdx.x;
    __shared__ float s_red[8];
    __shared__ float s_c[INNER];
    if (t < INNER) s_c[t] = context[b * INNER + t];
    __syncthreads();
    float acc = 0.f;
    const float* wr = Wcz + (size_t)t * INNER;
    #pragma unroll 8
    for (int k = 0; k < INNER; ++k) acc = fmaf(wr[k], s_c[k], acc);
    // LayerNorm over the 512 z values (one per thread)
    float mu = block_sum8(acc, s_red) * (1.f / CC);
    float d = acc - mu;
    float var = block_sum8(d * d, s_red) * (1.f / CC);
    float rstd = rsqrtf(var + EPSV);
    maskbuf[b * CC + t] = fsigmoid(fmaf(d * rstd, gamma[t], beta[t]));
}

// ---- kE: pass 3 over x. sigmoid(ctx) in-register, 16 channels per block.
__global__ __launch_bounds__(256) void kE(
    const float* __restrict__ x, const float* __restrict__ ctx_part,
    const float* __restrict__ maskbuf, float* __restrict__ out)
{
    const int t  = threadIdx.x;
    const int hw = blockIdx.x * 1024 + t * 4;
    const int c0 = blockIdx.y * 16;
    const int b  = blockIdx.z;
    const size_t pb = (size_t)b * 4 * HWN + hw;
    float4 p0 = *(const float4*)(ctx_part + pb);
    float4 p1 = *(const float4*)(ctx_part + pb + HWN);
    float4 p2 = *(const float4*)(ctx_part + pb + 2 * HWN);
    float4 p3 = *(const float4*)(ctx_part + pb + 3 * HWN);
    float4 sg;
    sg.x = fsigmoid((p0.x + p1.x) + (p2.x + p3.x));
    sg.y = fsigmoid((p0.y + p1.y) + (p2.y + p3.y));
    sg.z = fsigmoid((p0.z + p1.z) + (p2.z + p3.z));
    sg.w = fsigmoid((p0.w + p1.w) + (p2.w + p3.w));
    const float* mb = maskbuf + b * CC + c0;
    const size_t base = ((size_t)b * CC + c0) * HWN + hw;
    #pragma unroll 4
    for (int ci = 0; ci < 16; ++ci) {
        const float m = mb[ci];
        float4 xv = *(const float4*)(x + base + (size_t)ci * HWN);
        float4 o;
        o.x = xv.x * (m + sg.x);
        o.y = xv.y * (m + sg.y);
        o.z = xv.z * (m + sg.z);
        o.w = xv.w * (m + sg.w);
        *(float4*)(out + base + (size_t)ci * HWN) = o;
    }
}

extern "C" void kernel_launch(void* const* d_in, const int* in_sizes, int n_in,
                              void* d_out, int out_size, void* d_ws, size_t ws_size,
                              hipStream_t stream) {
    const float* x     = (const float*)d_in[0];
    const float* Wsq   = (const float*)d_in[1];
    const float* Wsv   = (const float*)d_in[2];
    const float* Wcq   = (const float*)d_in[3];
    const float* Wcv   = (const float*)d_in[4];
    const float* Wcz   = (const float*)d_in[5];
    const float* gamma = (const float*)d_in[6];
    const float* beta  = (const float*)d_in[7];
    float* out = (float*)d_out;
    float* ws  = (float*)d_ws;

    float* cm_part    = ws;            // [16][4][4096] = 262144
    float* xsum_part  = ws + 262144;   // [16][8][512]  = 65536 (reused as xw_part)
    float* ctx_part   = ws + 327680;   // [16][4][4096] = 262144
    float* cmstats    = ws + 589824;   // 32
    float* wsv_eff    = ws + 589856;   // 8192
    float* avg_logits = ws + 598048;   // 4096
    float* context    = ws + 602144;   // 4096
    float* maskbuf    = ws + 606240;   // 8192
    // total ~614432 floats (~2.4 MiB); fully written before read — no memset

    kA<<<dim3(8, 4, BB), 256, 0, stream>>>(x, Wcq, cm_part, xsum_part);
    kB1<<<dim3(BB, 5), 256, 0, stream>>>(Wsq, cm_part, xsum_part, cmstats, avg_logits);
    k2c_wsv<<<dim3(BB, 2), 256, 0, stream>>>(Wsv, avg_logits, wsv_eff);
    kC<<<dim3(8, 4, BB), 256, 0, stream>>>(x, wsv_eff, cm_part, cmstats, ctx_part, xsum_part);
    kD1<<<dim3(BB, 4), 256, 0, stream>>>(Wcv, xsum_part, context);
    kD2<<<BB, 512, 0, stream>>>(Wcz, context, gamma, beta, maskbuf);
    kE<<<dim3(4, 32, BB), 256, 0, stream>>>(x, ctx_part, maskbuf, out);
}